// Round 5
// baseline (381.933 us; speedup 1.0000x reference)
//
#include <hip/hip_runtime.h>
#include <hip/hip_bf16.h>

// 2-layer GCN, N=50000, E=800000, D_IN=256, H=256, D_OUT=128.
// Round 5: high-MLP gather (wave-per-node, 8B loads, 8-edge unroll,
// 4 nodes/block), faster scan. GEMM path unchanged from round 4.

typedef __attribute__((ext_vector_type(8))) short bf16x8;
typedef __attribute__((ext_vector_type(4))) float f32x4;

__device__ inline float bf2f(unsigned short u) {
    return __uint_as_float(((unsigned)u) << 16);
}
__device__ inline unsigned short f2bf(float f) {
    unsigned x = __float_as_uint(f);
    unsigned r = (x + 0x7fffu + ((x >> 16) & 1u)) >> 16;   // RNE
    return (unsigned short)r;
}
// packed bf16 pair (as u32) -> two fp32
__device__ inline float bflo(unsigned u) { return __uint_as_float(u << 16); }
__device__ inline float bfhi(unsigned u) { return __uint_as_float(u & 0xffff0000u); }

// ---------------- degree / dinv ----------------
__global__ void degree_kernel(const int* __restrict__ dst, unsigned* __restrict__ deg, int E) {
    int e = blockIdx.x * blockDim.x + threadIdx.x;
    if (e < E) atomicAdd(&deg[dst[e]], 1u);
}

__global__ void dinv_kernel(const unsigned* __restrict__ deg, float* __restrict__ dinv, int N) {
    int i = blockIdx.x * blockDim.x + threadIdx.x;
    if (i < N) dinv[i] = rsqrtf((float)(deg[i] + 1u));  // +1 self-loop
}

// ---------------- exclusive scan, 4 elems/thread (13 chunks for N=50K) ----
__global__ __launch_bounds__(1024) void scan_kernel(const unsigned* __restrict__ deg,
                                                    int* __restrict__ rowptr,
                                                    int* __restrict__ cursor, int N) {
    __shared__ int wsum[16];
    __shared__ int carry_s;
    const int t = threadIdx.x, lane = t & 63, w = t >> 6;
    if (t == 0) carry_s = 0;
    __syncthreads();
    for (int base = 0; base < N; base += 4096) {
        int i0 = base + t * 4;
        int v[4];
#pragma unroll
        for (int j = 0; j < 4; j++) {
            int i = i0 + j;
            v[j] = (i < N) ? (int)deg[i] : 0;
        }
        int s = v[0] + v[1] + v[2] + v[3];
        int x = s;
#pragma unroll
        for (int off = 1; off < 64; off <<= 1) {
            int y = __shfl_up(x, off, 64);
            if (lane >= off) x += y;
        }
        if (lane == 63) wsum[w] = x;
        __syncthreads();
        if (w == 0 && lane < 16) {
            int ss = wsum[lane];
#pragma unroll
            for (int off = 1; off < 16; off <<= 1) {
                int y = __shfl_up(ss, off, 16);
                if ((lane & 15) >= off) ss += y;
            }
            wsum[lane] = ss;
        }
        __syncthreads();
        int waveoff = (w == 0) ? 0 : wsum[w - 1];
        int c = carry_s;
        int run = c + waveoff + (x - s);   // exclusive prefix before this thread's 4
#pragma unroll
        for (int j = 0; j < 4; j++) {
            int i = i0 + j;
            if (i < N) { rowptr[i] = run; cursor[i] = run; }
            run += v[j];
        }
        __syncthreads();
        if (t == 1023) carry_s = c + waveoff + x;
        __syncthreads();
    }
    if (t == 0) rowptr[N] = carry_s;
}

// ---------------- CSR fill ----------------
__global__ __launch_bounds__(256) void fill_kernel(const int* __restrict__ src,
                                                   const int* __restrict__ dst,
                                                   const float* __restrict__ dinv,
                                                   int* __restrict__ cursor,
                                                   int* __restrict__ col,
                                                   float* __restrict__ wgt, int E) {
    int e = blockIdx.x * blockDim.x + threadIdx.x;
    if (e < E) {
        int d = dst[e];
        int s = src[e];
        int pos = atomicAdd(&cursor[d], 1);
        col[pos] = s;
        wgt[pos] = dinv[s] * dinv[d];
    }
}

// ---------------- fp32 -> bf16 convert (x) ----------------
__global__ __launch_bounds__(256) void convert_x_kernel(const float* __restrict__ in,
                                                        unsigned short* __restrict__ out,
                                                        long n4) {
    long i = (long)blockIdx.x * blockDim.x + threadIdx.x;
    if (i < n4) {
        float4 v = ((const float4*)in)[i];
        ushort4 o;
        o.x = f2bf(v.x); o.y = f2bf(v.y); o.z = f2bf(v.z); o.w = f2bf(v.w);
        ((ushort4*)out)[i] = o;
    }
}

// ---------------- fp32 W[K][Nw] -> bf16 WT[Nw][K] ----------------
__global__ __launch_bounds__(256) void convert_wt_kernel(const float* __restrict__ W,
                                                         unsigned short* __restrict__ WT,
                                                         int K, int Nw) {
    int id = blockIdx.x * blockDim.x + threadIdx.x;
    if (id < K * Nw) {
        int k = id / Nw;
        int n = id % Nw;
        WT[(long)n * K + k] = f2bf(W[id]);
    }
}

// ---------------- bf16 MFMA GEMM: C[M][Nc] = A[M,K] * BT[Nc,K]^T ----------
#define GBM 128
#define GBN 128
#define GBK 64
__global__ __launch_bounds__(256) void gemm_bf16(const unsigned short* __restrict__ A,
                                                 const unsigned short* __restrict__ BT,
                                                 unsigned short* __restrict__ C,
                                                 int M, int Nc, int K) {
    __shared__ __align__(16) unsigned short As[GBM * GBK];
    __shared__ __align__(16) unsigned short Bs[GBN * GBK];
    const int t = threadIdx.x;
    const int lane = t & 63;
    const int w = t >> 6;
    const int row0 = blockIdx.x * GBM;
    const int col0 = blockIdx.y * GBN;
    const int rb = (w >> 1) * 64;
    const int cb = (w & 1) * 64;

    f32x4 acc[4][4] = {};

    for (int kb = 0; kb < K; kb += GBK) {
#pragma unroll
        for (int i = 0; i < 4; i++) {
            int p = i * 256 + t;
            int row = p >> 3;
            int slot = p & 7;
            int chunk = slot ^ (row & 7);
            int grow = row0 + row;
            if (grow >= M) grow = M - 1;
            const unsigned short* src = A + (size_t)grow * K + kb + chunk * 8;
            __builtin_amdgcn_global_load_lds(
                (const __attribute__((address_space(1))) void*)src,
                (__attribute__((address_space(3))) void*)&As[p * 8], 16, 0, 0);
        }
#pragma unroll
        for (int i = 0; i < 4; i++) {
            int p = i * 256 + t;
            int row = p >> 3;
            int slot = p & 7;
            int chunk = slot ^ (row & 7);
            const unsigned short* src = BT + (size_t)(col0 + row) * K + kb + chunk * 8;
            __builtin_amdgcn_global_load_lds(
                (const __attribute__((address_space(1))) void*)src,
                (__attribute__((address_space(3))) void*)&Bs[p * 8], 16, 0, 0);
        }
        asm volatile("s_waitcnt vmcnt(0)" ::: "memory");
        __syncthreads();

#pragma unroll
        for (int ks = 0; ks < 2; ks++) {
            int kq = ks * 4 + (lane >> 4);
            int rsel = lane & 15;
            bf16x8 af[4], bfr[4];
#pragma unroll
            for (int mt = 0; mt < 4; mt++) {
                int m = rb + mt * 16 + rsel;
                int slot = kq ^ (m & 7);
                af[mt] = *(const bf16x8*)&As[m * GBK + slot * 8];
            }
#pragma unroll
            for (int nt = 0; nt < 4; nt++) {
                int n = cb + nt * 16 + rsel;
                int slot = kq ^ (n & 7);
                bfr[nt] = *(const bf16x8*)&Bs[n * GBK + slot * 8];
            }
#pragma unroll
            for (int mt = 0; mt < 4; mt++)
#pragma unroll
                for (int nt = 0; nt < 4; nt++)
                    acc[mt][nt] = __builtin_amdgcn_mfma_f32_16x16x32_bf16(
                        af[mt], bfr[nt], acc[mt][nt], 0, 0, 0);
        }
        __syncthreads();
    }

#pragma unroll
    for (int mt = 0; mt < 4; mt++) {
#pragma unroll
        for (int nt = 0; nt < 4; nt++) {
            int gcol = col0 + cb + nt * 16 + (lane & 15);
            int grow0 = row0 + rb + mt * 16 + 4 * (lane >> 4);
#pragma unroll
            for (int r = 0; r < 4; r++) {
                int g = grow0 + r;
                if (g < M) C[(size_t)g * Nc + gcol] = f2bf(acc[mt][nt][r]);
            }
        }
    }
}

// ---------------- gather v2: wave-per-node, high MLP --------------------
// VPL = features per lane (4 -> F=256 uint2 loads; 2 -> F=128 uint loads).
// 4 independent waves (nodes) per 256-thread block, no barriers.
template <int VPL, bool OUT_BF16>
__global__ __launch_bounds__(256) void gather_v2(const unsigned short* __restrict__ h,
                                                 const int* __restrict__ rowptr,
                                                 const int* __restrict__ col,
                                                 const float* __restrict__ wgt,
                                                 const float* __restrict__ dinv,
                                                 const float* __restrict__ bias,
                                                 void* __restrict__ out,
                                                 int N) {
    constexpr int F = VPL * 64;
    const int wv = threadIdx.x >> 6;
    const int lane = threadIdx.x & 63;
    const int node = blockIdx.x * 4 + wv;
    if (node >= N) return;
    const int f0 = lane * VPL;

    const int beg = __builtin_amdgcn_readfirstlane(rowptr[node]);
    const int end = __builtin_amdgcn_readfirstlane(rowptr[node + 1]);

    float a[VPL];
#pragma unroll
    for (int k = 0; k < VPL; k++) a[k] = 0.f;

    int e = beg;
    // 8-edge unrolled main loop: 8 outstanding vector loads per lane.
    for (; e + 8 <= end; e += 8) {
        int s[8]; float wvv[8];
#pragma unroll
        for (int j = 0; j < 8; j++) { s[j] = col[e + j]; wvv[j] = wgt[e + j]; }
        if (VPL == 4) {
            uint2 u[8];
#pragma unroll
            for (int j = 0; j < 8; j++)
                u[j] = *(const uint2*)&h[(size_t)s[j] * F + f0];
#pragma unroll
            for (int j = 0; j < 8; j++) {
                a[0] += bflo(u[j].x) * wvv[j];
                a[1] += bfhi(u[j].x) * wvv[j];
                a[2] += bflo(u[j].y) * wvv[j];
                a[3] += bfhi(u[j].y) * wvv[j];
            }
        } else {
            unsigned u[8];
#pragma unroll
            for (int j = 0; j < 8; j++)
                u[j] = *(const unsigned*)&h[(size_t)s[j] * F + f0];
#pragma unroll
            for (int j = 0; j < 8; j++) {
                a[0] += bflo(u[j]) * wvv[j];
                a[1] += bfhi(u[j]) * wvv[j];
            }
        }
    }
    // 4-edge chunk
    if (e + 4 <= end) {
        int s[4]; float wvv[4];
#pragma unroll
        for (int j = 0; j < 4; j++) { s[j] = col[e + j]; wvv[j] = wgt[e + j]; }
        if (VPL == 4) {
            uint2 u[4];
#pragma unroll
            for (int j = 0; j < 4; j++)
                u[j] = *(const uint2*)&h[(size_t)s[j] * F + f0];
#pragma unroll
            for (int j = 0; j < 4; j++) {
                a[0] += bflo(u[j].x) * wvv[j];
                a[1] += bfhi(u[j].x) * wvv[j];
                a[2] += bflo(u[j].y) * wvv[j];
                a[3] += bfhi(u[j].y) * wvv[j];
            }
        } else {
            unsigned u[4];
#pragma unroll
            for (int j = 0; j < 4; j++)
                u[j] = *(const unsigned*)&h[(size_t)s[j] * F + f0];
#pragma unroll
            for (int j = 0; j < 4; j++) {
                a[0] += bflo(u[j]) * wvv[j];
                a[1] += bfhi(u[j]) * wvv[j];
            }
        }
        e += 4;
    }
    // remainder
    for (; e < end; e++) {
        int s = col[e];
        float wvv = wgt[e];
        if (VPL == 4) {
            uint2 u = *(const uint2*)&h[(size_t)s * F + f0];
            a[0] += bflo(u.x) * wvv;
            a[1] += bfhi(u.x) * wvv;
            a[2] += bflo(u.y) * wvv;
            a[3] += bfhi(u.y) * wvv;
        } else {
            unsigned u = *(const unsigned*)&h[(size_t)s * F + f0];
            a[0] += bflo(u) * wvv;
            a[1] += bfhi(u) * wvv;
        }
    }

    // self-loop + bias + relu
    float di = dinv[node];
    float sl = di * di;
    if (VPL == 4) {
        uint2 u = *(const uint2*)&h[(size_t)node * F + f0];
        float4 bv = *(const float4*)&bias[f0];
        float v0 = fmaxf(a[0] + bflo(u.x) * sl + bv.x, 0.f);
        float v1 = fmaxf(a[1] + bfhi(u.x) * sl + bv.y, 0.f);
        float v2 = fmaxf(a[2] + bflo(u.y) * sl + bv.z, 0.f);
        float v3 = fmaxf(a[3] + bfhi(u.y) * sl + bv.w, 0.f);
        if (OUT_BF16) {
            ushort4 o;
            o.x = f2bf(v0); o.y = f2bf(v1); o.z = f2bf(v2); o.w = f2bf(v3);
            *(ushort4*)&((unsigned short*)out)[(size_t)node * F + f0] = o;
        } else {
            float4 o = {v0, v1, v2, v3};
            *(float4*)&((float*)out)[(size_t)node * F + f0] = o;
        }
    } else {
        unsigned u = *(const unsigned*)&h[(size_t)node * F + f0];
        float2 bv = *(const float2*)&bias[f0];
        float v0 = fmaxf(a[0] + bflo(u) * sl + bv.x, 0.f);
        float v1 = fmaxf(a[1] + bfhi(u) * sl + bv.y, 0.f);
        if (OUT_BF16) {
            ushort2 o;
            o.x = f2bf(v0); o.y = f2bf(v1);
            *(ushort2*)&((unsigned short*)out)[(size_t)node * F + f0] = o;
        } else {
            float2 o = {v0, v1};
            *(float2*)&((float*)out)[(size_t)node * F + f0] = o;
        }
    }
}

extern "C" void kernel_launch(void* const* d_in, const int* in_sizes, int n_in,
                              void* d_out, int out_size, void* d_ws, size_t ws_size,
                              hipStream_t stream) {
    const float* x  = (const float*)d_in[0];   // [N, 256]
    const int* ei   = (const int*)d_in[1];     // [2, E] int32
    const float* W1 = (const float*)d_in[2];   // [256, 256]
    const float* b1 = (const float*)d_in[3];   // [256]
    const float* W2 = (const float*)d_in[4];   // [256, 128]
    const float* b2 = (const float*)d_in[5];   // [128]

    const int DIN = 256;
    const int N = in_sizes[0] / DIN;        // 50000
    const int E = in_sizes[1] / 2;          // 800000
    const int H = in_sizes[3];              // 256
    const int DOUT = in_sizes[5];           // 128

    const int* src = ei;
    const int* dst = ei + E;

    // workspace layout
    char* ws = (char*)d_ws;
    unsigned* deg = (unsigned*)ws;                   ws += (size_t)N * 4;
    float* dinv   = (float*)ws;                      ws += (size_t)N * 4;
    int* rowptr   = (int*)ws;                        ws += (size_t)(N + 4) * 4;
    int* cursor   = (int*)ws;                        ws += (size_t)N * 4;
    int* col      = (int*)ws;                        ws += (size_t)E * 4;
    float* wgt    = (float*)ws;                      ws += (size_t)E * 4;
    unsigned short* xb  = (unsigned short*)ws;       ws += (size_t)N * DIN * 2;
    unsigned short* w1t = (unsigned short*)ws;       ws += (size_t)DIN * H * 2;
    unsigned short* w2t = (unsigned short*)ws;       ws += (size_t)H * DOUT * 2;
    unsigned short* h1b = (unsigned short*)ws;       ws += (size_t)N * H * 2;
    unsigned short* y1b = (unsigned short*)ws;       ws += (size_t)N * H * 2;
    unsigned short* h2b = xb;                        // xb dead after gemm1
    float* outp = (float*)d_out;

    // ---- CSR build ----
    hipMemsetAsync(deg, 0, (size_t)N * 4, stream);
    degree_kernel<<<(E + 255) / 256, 256, 0, stream>>>(dst, deg, E);
    dinv_kernel<<<(N + 255) / 256, 256, 0, stream>>>(deg, dinv, N);
    scan_kernel<<<1, 1024, 0, stream>>>(deg, rowptr, cursor, N);
    fill_kernel<<<(E + 255) / 256, 256, 0, stream>>>(src, dst, dinv, cursor, col, wgt, E);

    // ---- conversions ----
    {
        long n4 = (long)N * DIN / 4;
        convert_x_kernel<<<(int)((n4 + 255) / 256), 256, 0, stream>>>(x, xb, n4);
        convert_wt_kernel<<<(DIN * H + 255) / 256, 256, 0, stream>>>(W1, w1t, DIN, H);
        convert_wt_kernel<<<(H * DOUT + 255) / 256, 256, 0, stream>>>(W2, w2t, H, DOUT);
    }

    // ---- layer 1 ----
    {
        dim3 grid((N + GBM - 1) / GBM, H / GBN);
        gemm_bf16<<<grid, 256, 0, stream>>>(xb, w1t, h1b, N, H, DIN);
    }
    gather_v2<4, true><<<(N + 3) / 4, 256, 0, stream>>>(h1b, rowptr, col, wgt, dinv, b1, y1b, N);

    // ---- layer 2 ----
    {
        dim3 grid((N + GBM - 1) / GBM, DOUT / GBN);
        gemm_bf16<<<grid, 256, 0, stream>>>(y1b, w2t, h2b, N, DOUT, H);
    }
    gather_v2<2, false><<<(N + 3) / 4, 256, 0, stream>>>(h2b, rowptr, col, wgt, dinv, b2, outp, N);
}